// Round 21
// baseline (176.519 us; speedup 1.0000x reference)
//
#include <hip/hip_runtime.h>
#include <math.h>

// GraphSAGE 2-layer + MLP head + softmax(2).
// 6-dispatch pipeline:
//   memset(cursor) -> fused_bin_gemm (bin edges || layer-1 MFMA GEMM)
//   -> build_csr2 (inline scan) -> fused_agg_gemm (agg1 -> LDS -> layer-2 GEMM)
//   -> agg_sig_bf (agg2: t2,r2 -> h2) -> head_k (MLP head + softmax).
// h1 never touches global. h2 aliases dead t1/r1; bins aliases t2.
// Grids sized one 64-node chunk per block (occupancy = LDS-limited 5/CU).
// Uses mean linearity: mean(X[nbrs])@Wl == mean((X@Wl)[nbrs]).

#define NF1 48
#define HH 64
#define BKT_SHIFT 8
#define BKT_SZ (1 << BKT_SHIFT)   // 256
#define BCAP 4800  // per-bucket capacity; mean ~4092, std ~64 -> +11 sigma
#define EPB 16     // edges per thread in bin phase

typedef __attribute__((ext_vector_type(8))) short short8v;   // 8 bf16 (4 VGPR)
typedef __attribute__((ext_vector_type(4))) float float4v;   // 4 f32 acc

__device__ __forceinline__ float sigmoidf_(float v) {
  return 1.0f / (1.0f + __expf(-v));
}
__device__ __forceinline__ float bflo(unsigned w) {
  union { unsigned u; float f; } c; c.u = w << 16; return c.f;
}
__device__ __forceinline__ float bfhi(unsigned w) {
  union { unsigned u; float f; } c; c.u = w & 0xffff0000u; return c.f;
}
__device__ __forceinline__ unsigned short f2bf(float f) {
  union { float f; unsigned u; } c; c.f = f;
  unsigned r = c.u + 0x7fffu + ((c.u >> 16) & 1u);  // RNE
  return (unsigned short)(r >> 16);
}

// ---------------- fused bin_edges || layer-1 GEMM ----------------
template <int K>
__global__ __launch_bounds__(256, 4) void fused_bin_gemm(
    const int* __restrict__ ei, int* __restrict__ cursor,
    unsigned* __restrict__ bins, int E, int NB,
    const float* __restrict__ X, const float* __restrict__ Wl,
    const float* __restrict__ Wr, const float* __restrict__ bias,
    unsigned short* __restrict__ t_out, float* __restrict__ r_out,
    int n_nodes, int abk, int gemmb) {
  __shared__ __align__(16) char smem[3 * 64 * 72 * 2];  // 27648 B arena

  if ((int)blockIdx.x < abk) {
    // ---- bin_edges path ----
    int* hist = (int*)smem;          // [512]
    int* gbase = hist + 512;         // [512]
    for (int i = threadIdx.x; i < NB; i += 256) hist[i] = 0;
    __syncthreads();
    int base_e = blockIdx.x * (256 * EPB) + threadIdx.x;
    unsigned pk[EPB];
    int bk[EPB], rk[EPB];
#pragma unroll
    for (int k = 0; k < EPB; k++) {
      int e = base_e + k * 256;
      bk[k] = -1;
      if (e < E) {
        int s = ei[e], d = ei[E + e];
        int b = d >> BKT_SHIFT;
        pk[k] = ((unsigned)(d & (BKT_SZ - 1)) << 23) | (unsigned)s;
        bk[k] = b;
        rk[k] = atomicAdd(&hist[b], 1);
      }
    }
    __syncthreads();
    for (int i = threadIdx.x; i < NB; i += 256) {
      int c = hist[i];
      gbase[i] = (c > 0) ? atomicAdd(&cursor[i], c) : 0;
    }
    __syncthreads();
#pragma unroll
    for (int k = 0; k < EPB; k++) {
      if (bk[k] >= 0) {
        int pos = gbase[bk[k]] + rk[k];
        bins[(size_t)bk[k] * BCAP + pos] = pk[k];
      }
    }
    return;
  }

  // ---- gemm path ----
  short(*sA)[72] = (short(*)[72])smem;
  short(*sWl)[72] = (short(*)[72])(smem + 9216);
  short(*sWr)[72] = (short(*)[72])(smem + 18432);
  int gbid = (int)blockIdx.x - abk;
  int lane = threadIdx.x & 63, wv = threadIdx.x >> 6;
  int l15 = lane & 15, kq = lane >> 4;

  for (int i = threadIdx.x; i < 64 * 64; i += 256) {
    int k = i >> 6, j = i & 63;
    short vl = 0, vr = 0;
    if (k < K) {
      vl = (short)f2bf(Wl[k * 64 + j]);
      vr = (short)f2bf(Wr[k * 64 + j]);
    }
    sWl[j][k] = vl;
    sWr[j][k] = vr;
  }
  if (K < 64) {
    constexpr int PADW = (64 - K) / 2;
    for (int i = threadIdx.x; i < 64 * PADW; i += 256) {
      int row = i / PADW, p = i % PADW;
      *(unsigned*)&sA[row][K + 2 * p] = 0u;
    }
  }
  float bcol[4];
#pragma unroll
  for (int c = 0; c < 4; c++) bcol[c] = bias[c * 16 + l15];

  for (int nbase = gbid * 64; nbase < n_nodes; nbase += gemmb * 64) {
    __syncthreads();
    for (int i = threadIdx.x; i < 64 * (K / 4); i += 256) {
      int row = i / (K / 4), c4 = i % (K / 4);
      int rr = nbase + row;
      if (rr >= n_nodes) rr = n_nodes - 1;
      float4 xv = ((const float4*)(X + (size_t)rr * K))[c4];
      unsigned lo = ((unsigned)f2bf(xv.y) << 16) | (unsigned)f2bf(xv.x);
      unsigned hi = ((unsigned)f2bf(xv.w) << 16) | (unsigned)f2bf(xv.z);
      uint2 pk2 = {lo, hi};
      *(uint2*)&sA[row][c4 * 4] = pk2;
    }
    __syncthreads();

    float4v acc_t[4], acc_r[4];
#pragma unroll
    for (int c = 0; c < 4; c++) {
      acc_t[c] = (float4v){0.0f, 0.0f, 0.0f, 0.0f};
      acc_r[c] = (float4v){bcol[c], bcol[c], bcol[c], bcol[c]};
    }
#pragma unroll
    for (int s = 0; s < 2; s++) {
      short8v af = *(const short8v*)&sA[wv * 16 + l15][s * 32 + kq * 8];
#pragma unroll
      for (int c = 0; c < 4; c++) {
        short8v bl = *(const short8v*)&sWl[c * 16 + l15][s * 32 + kq * 8];
        short8v br = *(const short8v*)&sWr[c * 16 + l15][s * 32 + kq * 8];
        acc_t[c] = __builtin_amdgcn_mfma_f32_16x16x32_bf16(af, bl, acc_t[c], 0, 0, 0);
        acc_r[c] = __builtin_amdgcn_mfma_f32_16x16x32_bf16(af, br, acc_r[c], 0, 0, 0);
      }
    }
#pragma unroll
    for (int c = 0; c < 4; c++) {
      int j = c * 16 + l15;
#pragma unroll
      for (int g = 0; g < 4; g++) {
        int node = nbase + wv * 16 + kq * 4 + g;
        if (node < n_nodes) {
          t_out[(size_t)node * HH + j] = f2bf(acc_t[c][g]);
          r_out[(size_t)node * HH + j] = acc_r[c][g];
        }
      }
    }
  }
}

// ---------------- build_csr with inline base ----------------
__global__ __launch_bounds__(256) void build_csr2(
    const unsigned* __restrict__ bins, const int* __restrict__ cursor,
    int* __restrict__ rp, int* __restrict__ csr, int n_nodes, int E, int NB) {
  __shared__ int hist[BKT_SZ];
  __shared__ int aa[BKT_SZ], bb[BKT_SZ];
  __shared__ int cur[BKT_SZ];
  int b = blockIdx.x;
  int tid = threadIdx.x;
  int node0 = b << BKT_SHIFT;
  int cnt = cursor[b];
  const unsigned* bp = bins + (size_t)b * BCAP;

  int part = 0;
  for (int i = tid; i < b; i += 256) part += cursor[i];
  aa[tid] = part;
  __syncthreads();
  for (int off = 128; off > 0; off >>= 1) {
    if (tid < off) aa[tid] += aa[tid + off];
    __syncthreads();
  }
  int gb = aa[0];
  __syncthreads();

  hist[tid] = 0;
  __syncthreads();
  for (int i = tid; i < cnt; i += 256) {
    atomicAdd(&hist[bp[i] >> 23], 1);
  }
  __syncthreads();
  int v = hist[tid];
  aa[tid] = v;
  __syncthreads();
  int* s = aa;
  int* d = bb;
  for (int off = 1; off < BKT_SZ; off <<= 1) {
    int t = s[tid] + ((tid >= off) ? s[tid - off] : 0);
    d[tid] = t;
    __syncthreads();
    int* tmp = s; s = d; d = tmp;
  }
  int loc = s[tid] - v;
  int node = node0 + tid;
  if (node < n_nodes) rp[node] = gb + loc;
  if (b == NB - 1 && tid == 0) rp[n_nodes] = E;
  cur[tid] = gb + loc;
  __syncthreads();
  for (int i = tid; i < cnt; i += 256) {
    unsigned p = bp[i];
    int dl = (int)(p >> 23);
    int pos = atomicAdd(&cur[dl], 1);
    csr[pos] = (int)(p & 0x7FFFFFu);
  }
}

// gather body: accumulates a0..a3 for a node's neighbors (cols 4q..4q+3)
__device__ __forceinline__ void gather4(const uint2* __restrict__ tb,
                                        const int* __restrict__ csr,
                                        int rs, int re,
                                        float& a0, float& a1, float& a2, float& a3) {
  int j = rs;
  for (; j + 7 < re; j += 8) {
    uint2 u0 = tb[(size_t)csr[j + 0] * 16];
    uint2 u1 = tb[(size_t)csr[j + 1] * 16];
    uint2 u2 = tb[(size_t)csr[j + 2] * 16];
    uint2 u3 = tb[(size_t)csr[j + 3] * 16];
    uint2 u4 = tb[(size_t)csr[j + 4] * 16];
    uint2 u5 = tb[(size_t)csr[j + 5] * 16];
    uint2 u6 = tb[(size_t)csr[j + 6] * 16];
    uint2 u7 = tb[(size_t)csr[j + 7] * 16];
    a0 += ((bflo(u0.x) + bflo(u1.x)) + (bflo(u2.x) + bflo(u3.x))) +
          ((bflo(u4.x) + bflo(u5.x)) + (bflo(u6.x) + bflo(u7.x)));
    a1 += ((bfhi(u0.x) + bfhi(u1.x)) + (bfhi(u2.x) + bfhi(u3.x))) +
          ((bfhi(u4.x) + bfhi(u5.x)) + (bfhi(u6.x) + bfhi(u7.x)));
    a2 += ((bflo(u0.y) + bflo(u1.y)) + (bflo(u2.y) + bflo(u3.y))) +
          ((bflo(u4.y) + bflo(u5.y)) + (bflo(u6.y) + bflo(u7.y)));
    a3 += ((bfhi(u0.y) + bfhi(u1.y)) + (bfhi(u2.y) + bfhi(u3.y))) +
          ((bfhi(u4.y) + bfhi(u5.y)) + (bfhi(u6.y) + bfhi(u7.y)));
  }
  if (j + 3 < re) {
    uint2 u0 = tb[(size_t)csr[j + 0] * 16];
    uint2 u1 = tb[(size_t)csr[j + 1] * 16];
    uint2 u2 = tb[(size_t)csr[j + 2] * 16];
    uint2 u3 = tb[(size_t)csr[j + 3] * 16];
    a0 += (bflo(u0.x) + bflo(u1.x)) + (bflo(u2.x) + bflo(u3.x));
    a1 += (bfhi(u0.x) + bfhi(u1.x)) + (bfhi(u2.x) + bfhi(u3.x));
    a2 += (bflo(u0.y) + bflo(u1.y)) + (bflo(u2.y) + bflo(u3.y));
    a3 += (bfhi(u0.y) + bfhi(u1.y)) + (bfhi(u2.y) + bfhi(u3.y));
    j += 4;
  }
  for (; j < re; j++) {
    uint2 u = tb[(size_t)csr[j] * 16];
    a0 += bflo(u.x);
    a1 += bfhi(u.x);
    a2 += bflo(u.y);
    a3 += bfhi(u.y);
  }
}

// ---------------- fused agg1 + layer-2 MFMA GEMM ----------------
__global__ __launch_bounds__(256, 4) void fused_agg_gemm(
    const unsigned short* __restrict__ t1, const float* __restrict__ r1,
    const int* __restrict__ rp, const int* __restrict__ csr,
    const float* __restrict__ W2l, const float* __restrict__ W2r,
    const float* __restrict__ b2l,
    unsigned short* __restrict__ t2, unsigned short* __restrict__ r2,
    int n_nodes, int gemmb) {
  __shared__ short sA[64][72];
  __shared__ short sWl[64][72];
  __shared__ short sWr[64][72];
  int lane = threadIdx.x & 63, wv = threadIdx.x >> 6;
  int l15 = lane & 15, kq = lane >> 4;
  int grp = threadIdx.x >> 4, q = threadIdx.x & 15;

  for (int i = threadIdx.x; i < 64 * 64; i += 256) {
    int k = i >> 6, j = i & 63;
    sWl[j][k] = (short)f2bf(W2l[k * 64 + j]);
    sWr[j][k] = (short)f2bf(W2r[k * 64 + j]);
  }
  float bcol[4];
#pragma unroll
  for (int c = 0; c < 4; c++) bcol[c] = b2l[c * 16 + l15];

  for (int nbase = blockIdx.x * 64; nbase < n_nodes; nbase += gemmb * 64) {
    __syncthreads();  // prev-iter LDS reads done / W staged
#pragma unroll
    for (int p = 0; p < 4; p++) {
      int row = p * 16 + grp;
      int node = nbase + row;
      int nn = node < n_nodes ? node : n_nodes - 1;
      int rs = rp[nn], re = rp[nn + 1];
      int deg = re - rs;
      const uint2* tb = (const uint2*)t1 + q;
      float a0 = 0, a1 = 0, a2 = 0, a3 = 0;
      gather4(tb, csr, rs, re, a0, a1, a2, a3);
      float inv = 1.0f / fmaxf((float)deg, 1.0f);
      float4 rv = ((const float4*)(r1 + (size_t)nn * HH))[q];
      float h0 = sigmoidf_(a0 * inv + rv.x);
      float h1v = sigmoidf_(a1 * inv + rv.y);
      float h2v = sigmoidf_(a2 * inv + rv.z);
      float h3v = sigmoidf_(a3 * inv + rv.w);
      unsigned lo = ((unsigned)f2bf(h1v) << 16) | (unsigned)f2bf(h0);
      unsigned hi = ((unsigned)f2bf(h3v) << 16) | (unsigned)f2bf(h2v);
      uint2 pk = {lo, hi};
      *(uint2*)&sA[row][q * 4] = pk;
    }
    __syncthreads();

    float4v acc_t[4], acc_r[4];
#pragma unroll
    for (int c = 0; c < 4; c++) {
      acc_t[c] = (float4v){0.0f, 0.0f, 0.0f, 0.0f};
      acc_r[c] = (float4v){bcol[c], bcol[c], bcol[c], bcol[c]};
    }
#pragma unroll
    for (int s = 0; s < 2; s++) {
      short8v af = *(const short8v*)&sA[wv * 16 + l15][s * 32 + kq * 8];
#pragma unroll
      for (int c = 0; c < 4; c++) {
        short8v bl = *(const short8v*)&sWl[c * 16 + l15][s * 32 + kq * 8];
        short8v br = *(const short8v*)&sWr[c * 16 + l15][s * 32 + kq * 8];
        acc_t[c] = __builtin_amdgcn_mfma_f32_16x16x32_bf16(af, bl, acc_t[c], 0, 0, 0);
        acc_r[c] = __builtin_amdgcn_mfma_f32_16x16x32_bf16(af, br, acc_r[c], 0, 0, 0);
      }
    }
#pragma unroll
    for (int c = 0; c < 4; c++) {
      int j = c * 16 + l15;
#pragma unroll
      for (int g = 0; g < 4; g++) {
        int node = nbase + wv * 16 + kq * 4 + g;
        if (node < n_nodes) {
          t2[(size_t)node * HH + j] = f2bf(acc_t[c][g]);
          r2[(size_t)node * HH + j] = f2bf(acc_r[c][g]);
        }
      }
    }
  }
}

// ---------------- lean agg2: h2 = sigmoid(mean(t2[nbrs]) + r2) ----------------
__global__ __launch_bounds__(256) void agg_sig_bf(
    const unsigned short* __restrict__ t, const unsigned short* __restrict__ r,
    const int* __restrict__ rp, const int* __restrict__ csr,
    float* __restrict__ h, int n_nodes) {
  int grp = threadIdx.x >> 4;
  int q = threadIdx.x & 15;
  int node = blockIdx.x * 16 + grp;
  if (node >= n_nodes) return;
  int rs = rp[node], re = rp[node + 1];
  int deg = re - rs;
  const uint2* tb = (const uint2*)t + q;

  float a0 = 0, a1 = 0, a2 = 0, a3 = 0;
  gather4(tb, csr, rs, re, a0, a1, a2, a3);

  float inv = 1.0f / fmaxf((float)deg, 1.0f);
  uint2 ru = ((const uint2*)(r + (size_t)node * HH))[q];
  float4 o;
  o.x = sigmoidf_(a0 * inv + bflo(ru.x));
  o.y = sigmoidf_(a1 * inv + bfhi(ru.x));
  o.z = sigmoidf_(a2 * inv + bflo(ru.y));
  o.w = sigmoidf_(a3 * inv + bfhi(ru.y));
  ((float4*)(h + (size_t)node * HH))[q] = o;
}

// ---------------- MLP head ----------------
__global__ __launch_bounds__(512, 4) void head_k(
    const float* __restrict__ h2,
    const float* __restrict__ Wlin1, const float* __restrict__ blin1,
    const float* __restrict__ Wlin2, const float* __restrict__ blin2,
    float* __restrict__ out, int n_nodes) {
  __shared__ float sx[64][HH];
  __shared__ float sh3[64][HH];
  __shared__ float sw2[HH * 2];
  int wv = threadIdx.x >> 6, lane = threadIdx.x & 63;

  float w1[HH];
#pragma unroll
  for (int k = 0; k < HH; k++) w1[k] = Wlin1[k * HH + lane];
  float bv = blin1[lane];
  if (threadIdx.x < HH * 2) sw2[threadIdx.x] = Wlin2[threadIdx.x];
  float sb20 = blin2[0], sb21 = blin2[1];

  for (int nbase = blockIdx.x * 64; nbase < n_nodes; nbase += gridDim.x * 64) {
    __syncthreads();
    for (int i = threadIdx.x; i < 64 * (HH / 4); i += 512) {
      int row = i >> 4, c4 = i & 15;
      int rr = nbase + row;
      if (rr >= n_nodes) rr = n_nodes - 1;
      ((float4*)sx[row])[c4] = ((const float4*)(h2 + (size_t)rr * HH))[c4];
    }
    __syncthreads();

    float acc[8];
#pragma unroll
    for (int m = 0; m < 8; m++) acc[m] = bv;
#pragma unroll
    for (int k = 0; k < HH; k += 4) {
#pragma unroll
      for (int m = 0; m < 8; m++) {
        float4 a = *(const float4*)&sx[wv * 8 + m][k];
        acc[m] += a.x * w1[k] + a.y * w1[k + 1] + a.z * w1[k + 2] + a.w * w1[k + 3];
      }
    }
#pragma unroll
    for (int m = 0; m < 8; m++) sh3[wv * 8 + m][lane] = sigmoidf_(acc[m]);
    __syncthreads();

    int node_l = threadIdx.x >> 3;
    int sub = threadIdx.x & 7;
    float l0 = 0.0f, l1 = 0.0f;
#pragma unroll
    for (int kk = 0; kk < 8; kk++) {
      int k = sub * 8 + kk;
      float v = sh3[node_l][k];
      l0 += v * sw2[k * 2 + 0];
      l1 += v * sw2[k * 2 + 1];
    }
    l0 += __shfl_xor(l0, 1); l1 += __shfl_xor(l1, 1);
    l0 += __shfl_xor(l0, 2); l1 += __shfl_xor(l1, 2);
    l0 += __shfl_xor(l0, 4); l1 += __shfl_xor(l1, 4);
    int node = nbase + node_l;
    if (sub == 0 && node < n_nodes) {
      l0 += sb20;
      l1 += sb21;
      float mx = fmaxf(l0, l1);
      float p0 = __expf(l0 - mx), p1 = __expf(l1 - mx);
      float s = 1.0f / (p0 + p1);
      float2 o2 = {p0 * s, p1 * s};
      ((float2*)out)[node] = o2;
    }
  }
}

extern "C" void kernel_launch(void* const* d_in, const int* in_sizes, int n_in,
                              void* d_out, int out_size, void* d_ws, size_t ws_size,
                              hipStream_t stream) {
  const float* x     = (const float*)d_in[0];
  const int*   ei    = (const int*)d_in[1];
  const float* W1l   = (const float*)d_in[2];
  const float* b1l   = (const float*)d_in[3];
  const float* W1r   = (const float*)d_in[4];
  const float* W2l   = (const float*)d_in[5];
  const float* b2l   = (const float*)d_in[6];
  const float* W2r   = (const float*)d_in[7];
  const float* Wlin1 = (const float*)d_in[8];
  const float* blin1 = (const float*)d_in[9];
  const float* Wlin2 = (const float*)d_in[10];
  const float* blin2 = (const float*)d_in[11];
  float* out = (float*)d_out;

  int n = in_sizes[0] / NF1;
  int E = in_sizes[1] / 2;
  int NB = (n + BKT_SZ - 1) >> BKT_SHIFT;  // 391 (<= 512)

  int* cursor = (int*)d_ws;                 // [NB]
  int* rp     = cursor + NB;                // [n+1]
  int* csr    = rp + n + 1;                 // [E]
  size_t off = (size_t)(NB + n + 1 + E) * sizeof(int);
  off = (off + 255) & ~(size_t)255;
  size_t t1_off = off;
  unsigned short* t1 = (unsigned short*)((char*)d_ws + off);  // [n,64] bf16
  off += (size_t)n * HH * sizeof(unsigned short);
  off = (off + 255) & ~(size_t)255;
  float* r1 = (float*)((char*)d_ws + off);                    // [n,64] f32
  off += (size_t)n * HH * sizeof(float);
  off = (off + 255) & ~(size_t)255;
  unsigned short* t2 = (unsigned short*)((char*)d_ws + off);  // [n,64] bf16
  off += (size_t)n * HH * sizeof(unsigned short);
  off = (off + 255) & ~(size_t)255;
  unsigned short* r2 = (unsigned short*)((char*)d_ws + off);  // [n,64] bf16
  // bins aliases t2 (bins dead after build_csr2; t2 first written after).
  unsigned* bins = (unsigned*)t2;
  // h2 aliases t1+r1 region (both dead after fused_agg_gemm).
  float* h2 = (float*)((char*)d_ws + t1_off);

  hipMemsetAsync(cursor, 0, (size_t)NB * sizeof(int), stream);

  int abk = (E + 256 * EPB - 1) / (256 * EPB);   // 391
  int chunks = (n + 63) / 64;                    // 1563
  int gemmb = chunks;                            // one chunk per block
  int aggb = (n + 15) / 16;
  int headb = chunks;

  // bin_edges (blocks [0,abk)) || layer-1 GEMM (blocks [abk, abk+gemmb))
  fused_bin_gemm<NF1><<<abk + gemmb, 256, 0, stream>>>(
      ei, cursor, bins, E, NB, x, W1l, W1r, b1l, t1, r1, n, abk, gemmb);

  build_csr2<<<NB, 256, 0, stream>>>(bins, cursor, rp, csr, n, E, NB);

  // agg1 (t1,r1 -> h1 in LDS) + layer-2 GEMM -> t2, r2 (bf16)
  fused_agg_gemm<<<gemmb, 256, 0, stream>>>(t1, r1, rp, csr, W2l, W2r, b2l,
                                            t2, r2, n, gemmb);

  // agg2: h2 = sigmoid(mean(t2[nbrs]) + r2)   (writes over dead t1/r1)
  agg_sig_bf<<<aggb, 256, 0, stream>>>(t2, r2, rp, csr, h2, n);

  // MLP head
  head_k<<<headb, 512, 0, stream>>>(h2, Wlin1, blin1, Wlin2, blin2, out, n);
}

// Round 22
// 167.239 us; speedup vs baseline: 1.0555x; 1.0555x over previous
//
#include <hip/hip_runtime.h>
#include <math.h>

// GraphSAGE 2-layer + MLP head + softmax(2).
// 6-dispatch pipeline:
//   memset(cursor) -> fused_bin_gemm (bin edges || layer-1 MFMA GEMM)
//   -> build_csr2 (inline scan) -> fused_agg_gemm (agg1 -> LDS -> layer-2 GEMM)
//   -> agg_sig_bf (agg2: t2,r2 -> h2) -> head_k (MLP head + softmax).
// h1 never touches global. h2 aliases dead t1/r1; bins aliases t2.
// fused_agg_gemm phase A: 8-lane groups, uint4 row loads, 2 serial passes.
// Uses mean linearity: mean(X[nbrs])@Wl == mean((X@Wl)[nbrs]).

#define NF1 48
#define HH 64
#define BKT_SHIFT 8
#define BKT_SZ (1 << BKT_SHIFT)   // 256
#define BCAP 4800  // per-bucket capacity; mean ~4092, std ~64 -> +11 sigma
#define EPB 16     // edges per thread in bin phase

typedef __attribute__((ext_vector_type(8))) short short8v;   // 8 bf16 (4 VGPR)
typedef __attribute__((ext_vector_type(4))) float float4v;   // 4 f32 acc

__device__ __forceinline__ float sigmoidf_(float v) {
  return 1.0f / (1.0f + __expf(-v));
}
__device__ __forceinline__ float bflo(unsigned w) {
  union { unsigned u; float f; } c; c.u = w << 16; return c.f;
}
__device__ __forceinline__ float bfhi(unsigned w) {
  union { unsigned u; float f; } c; c.u = w & 0xffff0000u; return c.f;
}
__device__ __forceinline__ unsigned short f2bf(float f) {
  union { float f; unsigned u; } c; c.f = f;
  unsigned r = c.u + 0x7fffu + ((c.u >> 16) & 1u);  // RNE
  return (unsigned short)(r >> 16);
}

// ---------------- fused bin_edges || layer-1 GEMM ----------------
template <int K>
__global__ __launch_bounds__(256, 4) void fused_bin_gemm(
    const int* __restrict__ ei, int* __restrict__ cursor,
    unsigned* __restrict__ bins, int E, int NB,
    const float* __restrict__ X, const float* __restrict__ Wl,
    const float* __restrict__ Wr, const float* __restrict__ bias,
    unsigned short* __restrict__ t_out, float* __restrict__ r_out,
    int n_nodes, int abk, int gemmb) {
  __shared__ __align__(16) char smem[3 * 64 * 72 * 2];  // 27648 B arena

  if ((int)blockIdx.x < abk) {
    // ---- bin_edges path ----
    int* hist = (int*)smem;          // [512]
    int* gbase = hist + 512;         // [512]
    for (int i = threadIdx.x; i < NB; i += 256) hist[i] = 0;
    __syncthreads();
    int base_e = blockIdx.x * (256 * EPB) + threadIdx.x;
    unsigned pk[EPB];
    int bk[EPB], rk[EPB];
#pragma unroll
    for (int k = 0; k < EPB; k++) {
      int e = base_e + k * 256;
      bk[k] = -1;
      if (e < E) {
        int s = ei[e], d = ei[E + e];
        int b = d >> BKT_SHIFT;
        pk[k] = ((unsigned)(d & (BKT_SZ - 1)) << 23) | (unsigned)s;
        bk[k] = b;
        rk[k] = atomicAdd(&hist[b], 1);
      }
    }
    __syncthreads();
    for (int i = threadIdx.x; i < NB; i += 256) {
      int c = hist[i];
      gbase[i] = (c > 0) ? atomicAdd(&cursor[i], c) : 0;
    }
    __syncthreads();
#pragma unroll
    for (int k = 0; k < EPB; k++) {
      if (bk[k] >= 0) {
        int pos = gbase[bk[k]] + rk[k];
        bins[(size_t)bk[k] * BCAP + pos] = pk[k];
      }
    }
    return;
  }

  // ---- gemm path ----
  short(*sA)[72] = (short(*)[72])smem;
  short(*sWl)[72] = (short(*)[72])(smem + 9216);
  short(*sWr)[72] = (short(*)[72])(smem + 18432);
  int gbid = (int)blockIdx.x - abk;
  int lane = threadIdx.x & 63, wv = threadIdx.x >> 6;
  int l15 = lane & 15, kq = lane >> 4;

  for (int i = threadIdx.x; i < 64 * 64; i += 256) {
    int k = i >> 6, j = i & 63;
    short vl = 0, vr = 0;
    if (k < K) {
      vl = (short)f2bf(Wl[k * 64 + j]);
      vr = (short)f2bf(Wr[k * 64 + j]);
    }
    sWl[j][k] = vl;
    sWr[j][k] = vr;
  }
  if (K < 64) {
    constexpr int PADW = (64 - K) / 2;
    for (int i = threadIdx.x; i < 64 * PADW; i += 256) {
      int row = i / PADW, p = i % PADW;
      *(unsigned*)&sA[row][K + 2 * p] = 0u;
    }
  }
  float bcol[4];
#pragma unroll
  for (int c = 0; c < 4; c++) bcol[c] = bias[c * 16 + l15];

  for (int nbase = gbid * 64; nbase < n_nodes; nbase += gemmb * 64) {
    __syncthreads();
    for (int i = threadIdx.x; i < 64 * (K / 4); i += 256) {
      int row = i / (K / 4), c4 = i % (K / 4);
      int rr = nbase + row;
      if (rr >= n_nodes) rr = n_nodes - 1;
      float4 xv = ((const float4*)(X + (size_t)rr * K))[c4];
      unsigned lo = ((unsigned)f2bf(xv.y) << 16) | (unsigned)f2bf(xv.x);
      unsigned hi = ((unsigned)f2bf(xv.w) << 16) | (unsigned)f2bf(xv.z);
      uint2 pk2 = {lo, hi};
      *(uint2*)&sA[row][c4 * 4] = pk2;
    }
    __syncthreads();

    float4v acc_t[4], acc_r[4];
#pragma unroll
    for (int c = 0; c < 4; c++) {
      acc_t[c] = (float4v){0.0f, 0.0f, 0.0f, 0.0f};
      acc_r[c] = (float4v){bcol[c], bcol[c], bcol[c], bcol[c]};
    }
#pragma unroll
    for (int s = 0; s < 2; s++) {
      short8v af = *(const short8v*)&sA[wv * 16 + l15][s * 32 + kq * 8];
#pragma unroll
      for (int c = 0; c < 4; c++) {
        short8v bl = *(const short8v*)&sWl[c * 16 + l15][s * 32 + kq * 8];
        short8v br = *(const short8v*)&sWr[c * 16 + l15][s * 32 + kq * 8];
        acc_t[c] = __builtin_amdgcn_mfma_f32_16x16x32_bf16(af, bl, acc_t[c], 0, 0, 0);
        acc_r[c] = __builtin_amdgcn_mfma_f32_16x16x32_bf16(af, br, acc_r[c], 0, 0, 0);
      }
    }
#pragma unroll
    for (int c = 0; c < 4; c++) {
      int j = c * 16 + l15;
#pragma unroll
      for (int g = 0; g < 4; g++) {
        int node = nbase + wv * 16 + kq * 4 + g;
        if (node < n_nodes) {
          t_out[(size_t)node * HH + j] = f2bf(acc_t[c][g]);
          r_out[(size_t)node * HH + j] = acc_r[c][g];
        }
      }
    }
  }
}

// ---------------- build_csr with inline base ----------------
__global__ __launch_bounds__(256) void build_csr2(
    const unsigned* __restrict__ bins, const int* __restrict__ cursor,
    int* __restrict__ rp, int* __restrict__ csr, int n_nodes, int E, int NB) {
  __shared__ int hist[BKT_SZ];
  __shared__ int aa[BKT_SZ], bb[BKT_SZ];
  __shared__ int cur[BKT_SZ];
  int b = blockIdx.x;
  int tid = threadIdx.x;
  int node0 = b << BKT_SHIFT;
  int cnt = cursor[b];
  const unsigned* bp = bins + (size_t)b * BCAP;

  int part = 0;
  for (int i = tid; i < b; i += 256) part += cursor[i];
  aa[tid] = part;
  __syncthreads();
  for (int off = 128; off > 0; off >>= 1) {
    if (tid < off) aa[tid] += aa[tid + off];
    __syncthreads();
  }
  int gb = aa[0];
  __syncthreads();

  hist[tid] = 0;
  __syncthreads();
  for (int i = tid; i < cnt; i += 256) {
    atomicAdd(&hist[bp[i] >> 23], 1);
  }
  __syncthreads();
  int v = hist[tid];
  aa[tid] = v;
  __syncthreads();
  int* s = aa;
  int* d = bb;
  for (int off = 1; off < BKT_SZ; off <<= 1) {
    int t = s[tid] + ((tid >= off) ? s[tid - off] : 0);
    d[tid] = t;
    __syncthreads();
    int* tmp = s; s = d; d = tmp;
  }
  int loc = s[tid] - v;
  int node = node0 + tid;
  if (node < n_nodes) rp[node] = gb + loc;
  if (b == NB - 1 && tid == 0) rp[n_nodes] = E;
  cur[tid] = gb + loc;
  __syncthreads();
  for (int i = tid; i < cnt; i += 256) {
    unsigned p = bp[i];
    int dl = (int)(p >> 23);
    int pos = atomicAdd(&cur[dl], 1);
    csr[pos] = (int)(p & 0x7FFFFFu);
  }
}

// gather body (16-lane groups, uint2): accumulates a0..a3 for cols 4q..4q+3
__device__ __forceinline__ void gather4(const uint2* __restrict__ tb,
                                        const int* __restrict__ csr,
                                        int rs, int re,
                                        float& a0, float& a1, float& a2, float& a3) {
  int j = rs;
  for (; j + 7 < re; j += 8) {
    uint2 u0 = tb[(size_t)csr[j + 0] * 16];
    uint2 u1 = tb[(size_t)csr[j + 1] * 16];
    uint2 u2 = tb[(size_t)csr[j + 2] * 16];
    uint2 u3 = tb[(size_t)csr[j + 3] * 16];
    uint2 u4 = tb[(size_t)csr[j + 4] * 16];
    uint2 u5 = tb[(size_t)csr[j + 5] * 16];
    uint2 u6 = tb[(size_t)csr[j + 6] * 16];
    uint2 u7 = tb[(size_t)csr[j + 7] * 16];
    a0 += ((bflo(u0.x) + bflo(u1.x)) + (bflo(u2.x) + bflo(u3.x))) +
          ((bflo(u4.x) + bflo(u5.x)) + (bflo(u6.x) + bflo(u7.x)));
    a1 += ((bfhi(u0.x) + bfhi(u1.x)) + (bfhi(u2.x) + bfhi(u3.x))) +
          ((bfhi(u4.x) + bfhi(u5.x)) + (bfhi(u6.x) + bfhi(u7.x)));
    a2 += ((bflo(u0.y) + bflo(u1.y)) + (bflo(u2.y) + bflo(u3.y))) +
          ((bflo(u4.y) + bflo(u5.y)) + (bflo(u6.y) + bflo(u7.y)));
    a3 += ((bfhi(u0.y) + bfhi(u1.y)) + (bfhi(u2.y) + bfhi(u3.y))) +
          ((bfhi(u4.y) + bfhi(u5.y)) + (bfhi(u6.y) + bfhi(u7.y)));
  }
  if (j + 3 < re) {
    uint2 u0 = tb[(size_t)csr[j + 0] * 16];
    uint2 u1 = tb[(size_t)csr[j + 1] * 16];
    uint2 u2 = tb[(size_t)csr[j + 2] * 16];
    uint2 u3 = tb[(size_t)csr[j + 3] * 16];
    a0 += (bflo(u0.x) + bflo(u1.x)) + (bflo(u2.x) + bflo(u3.x));
    a1 += (bfhi(u0.x) + bfhi(u1.x)) + (bfhi(u2.x) + bfhi(u3.x));
    a2 += (bflo(u0.y) + bflo(u1.y)) + (bflo(u2.y) + bflo(u3.y));
    a3 += (bfhi(u0.y) + bfhi(u1.y)) + (bfhi(u2.y) + bfhi(u3.y));
    j += 4;
  }
  for (; j < re; j++) {
    uint2 u = tb[(size_t)csr[j] * 16];
    a0 += bflo(u.x);
    a1 += bfhi(u.x);
    a2 += bflo(u.y);
    a3 += bfhi(u.y);
  }
}

// gather body (8-lane groups, uint4): accumulates a[0..7] for cols 8q..8q+7
__device__ __forceinline__ void gather8(const uint4* __restrict__ tb,
                                        const int* __restrict__ csr,
                                        int rs, int re, float* __restrict__ a) {
  int j = rs;
  for (; j + 7 < re; j += 8) {
    uint4 u0 = tb[(size_t)csr[j + 0] * 8];
    uint4 u1 = tb[(size_t)csr[j + 1] * 8];
    uint4 u2 = tb[(size_t)csr[j + 2] * 8];
    uint4 u3 = tb[(size_t)csr[j + 3] * 8];
    uint4 u4 = tb[(size_t)csr[j + 4] * 8];
    uint4 u5 = tb[(size_t)csr[j + 5] * 8];
    uint4 u6 = tb[(size_t)csr[j + 6] * 8];
    uint4 u7 = tb[(size_t)csr[j + 7] * 8];
    a[0] += ((bflo(u0.x) + bflo(u1.x)) + (bflo(u2.x) + bflo(u3.x))) +
            ((bflo(u4.x) + bflo(u5.x)) + (bflo(u6.x) + bflo(u7.x)));
    a[1] += ((bfhi(u0.x) + bfhi(u1.x)) + (bfhi(u2.x) + bfhi(u3.x))) +
            ((bfhi(u4.x) + bfhi(u5.x)) + (bfhi(u6.x) + bfhi(u7.x)));
    a[2] += ((bflo(u0.y) + bflo(u1.y)) + (bflo(u2.y) + bflo(u3.y))) +
            ((bflo(u4.y) + bflo(u5.y)) + (bflo(u6.y) + bflo(u7.y)));
    a[3] += ((bfhi(u0.y) + bfhi(u1.y)) + (bfhi(u2.y) + bfhi(u3.y))) +
            ((bfhi(u4.y) + bfhi(u5.y)) + (bfhi(u6.y) + bfhi(u7.y)));
    a[4] += ((bflo(u0.z) + bflo(u1.z)) + (bflo(u2.z) + bflo(u3.z))) +
            ((bflo(u4.z) + bflo(u5.z)) + (bflo(u6.z) + bflo(u7.z)));
    a[5] += ((bfhi(u0.z) + bfhi(u1.z)) + (bfhi(u2.z) + bfhi(u3.z))) +
            ((bfhi(u4.z) + bfhi(u5.z)) + (bfhi(u6.z) + bfhi(u7.z)));
    a[6] += ((bflo(u0.w) + bflo(u1.w)) + (bflo(u2.w) + bflo(u3.w))) +
            ((bflo(u4.w) + bflo(u5.w)) + (bflo(u6.w) + bflo(u7.w)));
    a[7] += ((bfhi(u0.w) + bfhi(u1.w)) + (bfhi(u2.w) + bfhi(u3.w))) +
            ((bfhi(u4.w) + bfhi(u5.w)) + (bfhi(u6.w) + bfhi(u7.w)));
  }
  if (j + 3 < re) {
    uint4 u0 = tb[(size_t)csr[j + 0] * 8];
    uint4 u1 = tb[(size_t)csr[j + 1] * 8];
    uint4 u2 = tb[(size_t)csr[j + 2] * 8];
    uint4 u3 = tb[(size_t)csr[j + 3] * 8];
    a[0] += (bflo(u0.x) + bflo(u1.x)) + (bflo(u2.x) + bflo(u3.x));
    a[1] += (bfhi(u0.x) + bfhi(u1.x)) + (bfhi(u2.x) + bfhi(u3.x));
    a[2] += (bflo(u0.y) + bflo(u1.y)) + (bflo(u2.y) + bflo(u3.y));
    a[3] += (bfhi(u0.y) + bfhi(u1.y)) + (bfhi(u2.y) + bfhi(u3.y));
    a[4] += (bflo(u0.z) + bflo(u1.z)) + (bflo(u2.z) + bflo(u3.z));
    a[5] += (bfhi(u0.z) + bfhi(u1.z)) + (bfhi(u2.z) + bfhi(u3.z));
    a[6] += (bflo(u0.w) + bflo(u1.w)) + (bflo(u2.w) + bflo(u3.w));
    a[7] += (bfhi(u0.w) + bfhi(u1.w)) + (bfhi(u2.w) + bfhi(u3.w));
    j += 4;
  }
  for (; j < re; j++) {
    uint4 u = tb[(size_t)csr[j] * 8];
    a[0] += bflo(u.x);
    a[1] += bfhi(u.x);
    a[2] += bflo(u.y);
    a[3] += bfhi(u.y);
    a[4] += bflo(u.z);
    a[5] += bfhi(u.z);
    a[6] += bflo(u.w);
    a[7] += bfhi(u.w);
  }
}

// ---------------- fused agg1 + layer-2 MFMA GEMM ----------------
// Phase A: 32 8-lane groups per block, 2 passes of 32 nodes; uint4 row loads.
__global__ __launch_bounds__(256, 4) void fused_agg_gemm(
    const unsigned short* __restrict__ t1, const float* __restrict__ r1,
    const int* __restrict__ rp, const int* __restrict__ csr,
    const float* __restrict__ W2l, const float* __restrict__ W2r,
    const float* __restrict__ b2l,
    unsigned short* __restrict__ t2, unsigned short* __restrict__ r2,
    int n_nodes, int gemmb) {
  __shared__ short sA[64][72];
  __shared__ short sWl[64][72];
  __shared__ short sWr[64][72];
  int lane = threadIdx.x & 63, wv = threadIdx.x >> 6;
  int l15 = lane & 15, kq = lane >> 4;
  int grp8 = threadIdx.x >> 3, q8 = threadIdx.x & 7;   // 32 groups of 8

  for (int i = threadIdx.x; i < 64 * 64; i += 256) {
    int k = i >> 6, j = i & 63;
    sWl[j][k] = (short)f2bf(W2l[k * 64 + j]);
    sWr[j][k] = (short)f2bf(W2r[k * 64 + j]);
  }
  float bcol[4];
#pragma unroll
  for (int c = 0; c < 4; c++) bcol[c] = b2l[c * 16 + l15];

  for (int nbase = blockIdx.x * 64; nbase < n_nodes; nbase += gemmb * 64) {
    __syncthreads();  // prev-iter LDS reads done / W staged
#pragma unroll
    for (int p = 0; p < 2; p++) {
      int row = p * 32 + grp8;
      int node = nbase + row;
      int nn = node < n_nodes ? node : n_nodes - 1;
      int rs = rp[nn], re = rp[nn + 1];
      int deg = re - rs;
      float a[8] = {0, 0, 0, 0, 0, 0, 0, 0};
      gather8((const uint4*)t1 + q8, csr, rs, re, a);
      float inv = 1.0f / fmaxf((float)deg, 1.0f);
      float4 rv0 = ((const float4*)(r1 + (size_t)nn * HH))[2 * q8];
      float4 rv1 = ((const float4*)(r1 + (size_t)nn * HH))[2 * q8 + 1];
      float h0 = sigmoidf_(a[0] * inv + rv0.x);
      float h1v = sigmoidf_(a[1] * inv + rv0.y);
      float h2v = sigmoidf_(a[2] * inv + rv0.z);
      float h3v = sigmoidf_(a[3] * inv + rv0.w);
      float h4v = sigmoidf_(a[4] * inv + rv1.x);
      float h5v = sigmoidf_(a[5] * inv + rv1.y);
      float h6v = sigmoidf_(a[6] * inv + rv1.z);
      float h7v = sigmoidf_(a[7] * inv + rv1.w);
      uint4 pk;
      pk.x = ((unsigned)f2bf(h1v) << 16) | (unsigned)f2bf(h0);
      pk.y = ((unsigned)f2bf(h3v) << 16) | (unsigned)f2bf(h2v);
      pk.z = ((unsigned)f2bf(h5v) << 16) | (unsigned)f2bf(h4v);
      pk.w = ((unsigned)f2bf(h7v) << 16) | (unsigned)f2bf(h6v);
      *(uint4*)&sA[row][q8 * 8] = pk;
    }
    __syncthreads();

    float4v acc_t[4], acc_r[4];
#pragma unroll
    for (int c = 0; c < 4; c++) {
      acc_t[c] = (float4v){0.0f, 0.0f, 0.0f, 0.0f};
      acc_r[c] = (float4v){bcol[c], bcol[c], bcol[c], bcol[c]};
    }
#pragma unroll
    for (int s = 0; s < 2; s++) {
      short8v af = *(const short8v*)&sA[wv * 16 + l15][s * 32 + kq * 8];
#pragma unroll
      for (int c = 0; c < 4; c++) {
        short8v bl = *(const short8v*)&sWl[c * 16 + l15][s * 32 + kq * 8];
        short8v br = *(const short8v*)&sWr[c * 16 + l15][s * 32 + kq * 8];
        acc_t[c] = __builtin_amdgcn_mfma_f32_16x16x32_bf16(af, bl, acc_t[c], 0, 0, 0);
        acc_r[c] = __builtin_amdgcn_mfma_f32_16x16x32_bf16(af, br, acc_r[c], 0, 0, 0);
      }
    }
#pragma unroll
    for (int c = 0; c < 4; c++) {
      int j = c * 16 + l15;
#pragma unroll
      for (int g = 0; g < 4; g++) {
        int node = nbase + wv * 16 + kq * 4 + g;
        if (node < n_nodes) {
          t2[(size_t)node * HH + j] = f2bf(acc_t[c][g]);
          r2[(size_t)node * HH + j] = f2bf(acc_r[c][g]);
        }
      }
    }
  }
}

// ---------------- lean agg2: h2 = sigmoid(mean(t2[nbrs]) + r2) ----------------
__global__ __launch_bounds__(256) void agg_sig_bf(
    const unsigned short* __restrict__ t, const unsigned short* __restrict__ r,
    const int* __restrict__ rp, const int* __restrict__ csr,
    float* __restrict__ h, int n_nodes) {
  int grp = threadIdx.x >> 4;
  int q = threadIdx.x & 15;
  int node = blockIdx.x * 16 + grp;
  if (node >= n_nodes) return;
  int rs = rp[node], re = rp[node + 1];
  int deg = re - rs;
  const uint2* tb = (const uint2*)t + q;

  float a0 = 0, a1 = 0, a2 = 0, a3 = 0;
  gather4(tb, csr, rs, re, a0, a1, a2, a3);

  float inv = 1.0f / fmaxf((float)deg, 1.0f);
  uint2 ru = ((const uint2*)(r + (size_t)node * HH))[q];
  float4 o;
  o.x = sigmoidf_(a0 * inv + bflo(ru.x));
  o.y = sigmoidf_(a1 * inv + bfhi(ru.x));
  o.z = sigmoidf_(a2 * inv + bflo(ru.y));
  o.w = sigmoidf_(a3 * inv + bfhi(ru.y));
  ((float4*)(h + (size_t)node * HH))[q] = o;
}

// ---------------- MLP head ----------------
__global__ __launch_bounds__(512, 4) void head_k(
    const float* __restrict__ h2,
    const float* __restrict__ Wlin1, const float* __restrict__ blin1,
    const float* __restrict__ Wlin2, const float* __restrict__ blin2,
    float* __restrict__ out, int n_nodes) {
  __shared__ float sx[64][HH];
  __shared__ float sh3[64][HH];
  __shared__ float sw2[HH * 2];
  int wv = threadIdx.x >> 6, lane = threadIdx.x & 63;

  float w1[HH];
#pragma unroll
  for (int k = 0; k < HH; k++) w1[k] = Wlin1[k * HH + lane];
  float bv = blin1[lane];
  if (threadIdx.x < HH * 2) sw2[threadIdx.x] = Wlin2[threadIdx.x];
  float sb20 = blin2[0], sb21 = blin2[1];

  for (int nbase = blockIdx.x * 64; nbase < n_nodes; nbase += gridDim.x * 64) {
    __syncthreads();
    for (int i = threadIdx.x; i < 64 * (HH / 4); i += 512) {
      int row = i >> 4, c4 = i & 15;
      int rr = nbase + row;
      if (rr >= n_nodes) rr = n_nodes - 1;
      ((float4*)sx[row])[c4] = ((const float4*)(h2 + (size_t)rr * HH))[c4];
    }
    __syncthreads();

    float acc[8];
#pragma unroll
    for (int m = 0; m < 8; m++) acc[m] = bv;
#pragma unroll
    for (int k = 0; k < HH; k += 4) {
#pragma unroll
      for (int m = 0; m < 8; m++) {
        float4 a = *(const float4*)&sx[wv * 8 + m][k];
        acc[m] += a.x * w1[k] + a.y * w1[k + 1] + a.z * w1[k + 2] + a.w * w1[k + 3];
      }
    }
#pragma unroll
    for (int m = 0; m < 8; m++) sh3[wv * 8 + m][lane] = sigmoidf_(acc[m]);
    __syncthreads();

    int node_l = threadIdx.x >> 3;
    int sub = threadIdx.x & 7;
    float l0 = 0.0f, l1 = 0.0f;
#pragma unroll
    for (int kk = 0; kk < 8; kk++) {
      int k = sub * 8 + kk;
      float v = sh3[node_l][k];
      l0 += v * sw2[k * 2 + 0];
      l1 += v * sw2[k * 2 + 1];
    }
    l0 += __shfl_xor(l0, 1); l1 += __shfl_xor(l1, 1);
    l0 += __shfl_xor(l0, 2); l1 += __shfl_xor(l1, 2);
    l0 += __shfl_xor(l0, 4); l1 += __shfl_xor(l1, 4);
    int node = nbase + node_l;
    if (sub == 0 && node < n_nodes) {
      l0 += sb20;
      l1 += sb21;
      float mx = fmaxf(l0, l1);
      float p0 = __expf(l0 - mx), p1 = __expf(l1 - mx);
      float s = 1.0f / (p0 + p1);
      float2 o2 = {p0 * s, p1 * s};
      ((float2*)out)[node] = o2;
    }
  }
}

extern "C" void kernel_launch(void* const* d_in, const int* in_sizes, int n_in,
                              void* d_out, int out_size, void* d_ws, size_t ws_size,
                              hipStream_t stream) {
  const float* x     = (const float*)d_in[0];
  const int*   ei    = (const int*)d_in[1];
  const float* W1l   = (const float*)d_in[2];
  const float* b1l   = (const float*)d_in[3];
  const float* W1r   = (const float*)d_in[4];
  const float* W2l   = (const float*)d_in[5];
  const float* b2l   = (const float*)d_in[6];
  const float* W2r   = (const float*)d_in[7];
  const float* Wlin1 = (const float*)d_in[8];
  const float* blin1 = (const float*)d_in[9];
  const float* Wlin2 = (const float*)d_in[10];
  const float* blin2 = (const float*)d_in[11];
  float* out = (float*)d_out;

  int n = in_sizes[0] / NF1;
  int E = in_sizes[1] / 2;
  int NB = (n + BKT_SZ - 1) >> BKT_SHIFT;  // 391 (<= 512)

  int* cursor = (int*)d_ws;                 // [NB]
  int* rp     = cursor + NB;                // [n+1]
  int* csr    = rp + n + 1;                 // [E]
  size_t off = (size_t)(NB + n + 1 + E) * sizeof(int);
  off = (off + 255) & ~(size_t)255;
  size_t t1_off = off;
  unsigned short* t1 = (unsigned short*)((char*)d_ws + off);  // [n,64] bf16
  off += (size_t)n * HH * sizeof(unsigned short);
  off = (off + 255) & ~(size_t)255;
  float* r1 = (float*)((char*)d_ws + off);                    // [n,64] f32
  off += (size_t)n * HH * sizeof(float);
  off = (off + 255) & ~(size_t)255;
  unsigned short* t2 = (unsigned short*)((char*)d_ws + off);  // [n,64] bf16
  off += (size_t)n * HH * sizeof(unsigned short);
  off = (off + 255) & ~(size_t)255;
  unsigned short* r2 = (unsigned short*)((char*)d_ws + off);  // [n,64] bf16
  // bins aliases t2 (bins dead after build_csr2; t2 first written after).
  unsigned* bins = (unsigned*)t2;
  // h2 aliases t1+r1 region (both dead after fused_agg_gemm).
  float* h2 = (float*)((char*)d_ws + t1_off);

  hipMemsetAsync(cursor, 0, (size_t)NB * sizeof(int), stream);

  int abk = (E + 256 * EPB - 1) / (256 * EPB);   // 391
  int chunks = (n + 63) / 64;                    // 1563
  int gemmb = chunks;
  int aggb = (n + 15) / 16;
  int headb = chunks;

  // bin_edges (blocks [0,abk)) || layer-1 GEMM (blocks [abk, abk+gemmb))
  fused_bin_gemm<NF1><<<abk + gemmb, 256, 0, stream>>>(
      ei, cursor, bins, E, NB, x, W1l, W1r, b1l, t1, r1, n, abk, gemmb);

  build_csr2<<<NB, 256, 0, stream>>>(bins, cursor, rp, csr, n, E, NB);

  // agg1 (t1,r1 -> h1 in LDS) + layer-2 GEMM -> t2, r2 (bf16)
  fused_agg_gemm<<<gemmb, 256, 0, stream>>>(t1, r1, rp, csr, W2l, W2r, b2l,
                                            t2, r2, n, gemmb);

  // agg2: h2 = sigmoid(mean(t2[nbrs]) + r2)   (writes over dead t1/r1)
  agg_sig_bf<<<aggb, 256, 0, stream>>>(t2, r2, rp, csr, h2, n);

  // MLP head
  head_k<<<headb, 512, 0, stream>>>(h2, Wlin1, blin1, Wlin2, blin2, out, n);
}